// Round 1
// baseline (291.710 us; speedup 1.0000x reference)
//
#include <hip/hip_runtime.h>

#define BN_EPS 1e-5f

__device__ __forceinline__ float wave_reduce_sum(float v) {
#pragma unroll
  for (int off = 1; off < 64; off <<= 1) v += __shfl_xor(v, off, 64);
  return v;
}

// ---------------------------------------------------------------------------
// Kernel 1: per-row embeddings -> fm_first (N x 576), plus
// partial[n] = sum(fm_first[n,:]) + fm_second_sum[n] + bias_vec[n]
// Layout: element idx = f*16 + e  (f in [0,36), e in [0,16))
// One wave (64 lanes) per row; 4 rows per 256-thread block.
// Each lane owns 9 elements (idx = lane + 64k) which all share e = lane&15.
// ---------------------------------------------------------------------------
__global__ __launch_bounds__(256) void embed_kernel(
    const float* __restrict__ Xi_dense, const float* __restrict__ Xv,
    const float* __restrict__ Wd, const float* __restrict__ bd,
    const float* __restrict__ tables, const int* __restrict__ Xi_cat,
    const float* __restrict__ bias_vec,
    float* __restrict__ fm_first, float* __restrict__ partial) {
  const int t = threadIdx.x;
  const int lane = t & 63;
  const int n = blockIdx.x * 4 + (t >> 6);

  const float* xv = Xv + n * 36;
  float sum_all = 0.f;  // sum over this thread's elements (for fm_first sum)
  float s_e = 0.f;      // sum over fields for this lane's e
  float q_e = 0.f;      // sum of squares for this lane's e

#pragma unroll
  for (int k = 0; k < 9; ++k) {
    const int idx = lane + 64 * k;
    const int f = idx >> 4;
    const int e = idx & 15;
    float val;
    if (f < 26) {
      val = Xi_dense[n * 26 + f] * Wd[f * 16 + e] + bd[f * 16 + e];
    } else {
      const int fc = f - 26;
      const int row = Xi_cat[n * 10 + fc];
      val = tables[(size_t)fc * 200000 * 16 + (size_t)row * 16 + e];
    }
    val *= xv[f];
    fm_first[(size_t)n * 576 + idx] = val;
    sum_all += val;
    s_e += val;
    q_e += val * val;
  }

  // reduce s,q across the 4 lanes sharing the same e (lanes differ by 16,32)
  float s_tot = s_e;
  s_tot += __shfl_xor(s_tot, 16, 64);
  s_tot += __shfl_xor(s_tot, 32, 64);
  float q_tot = q_e;
  q_tot += __shfl_xor(q_tot, 16, 64);
  q_tot += __shfl_xor(q_tot, 32, 64);

  const float fm2 = 0.5f * (s_tot * s_tot - q_tot);  // replicated 4x per e

  const float red1 = wave_reduce_sum(sum_all);        // = sum(fm_first row)
  const float red2 = wave_reduce_sum(fm2) * 0.25f;    // = fm_second row-sum

  if (lane == 0) partial[n] = red1 + red2 + bias_vec[n];
}

// ---------------------------------------------------------------------------
// Tiled fp32 GEMM: C(M x Nn) = op(A)(M x K) @ W^T(K x Nn) + bias
// W is (Nn x K) row-major. If TRANSFORM, A elements are mapped
// x -> ta[k]*x + tc[k] (BN affine on the K-dim) while loading.
// BM=128, BN=64, BK=16; 256 threads; 8x4 micro-tile per thread.
// Requires M%128==0, K%16==0; Nn guarded.
// ---------------------------------------------------------------------------
template <bool TRANSFORM>
__global__ __launch_bounds__(256) void gemm_tn(
    const float* __restrict__ A, const float* __restrict__ W,
    const float* __restrict__ bias, const float* __restrict__ ta,
    const float* __restrict__ tc, float* __restrict__ C, int M, int Nn,
    int K) {
  constexpr int BM = 128, BN = 64, BK = 16;
  __shared__ __align__(16) float As[BK][BM];
  __shared__ __align__(16) float Bs[BK][BN];

  const int t = threadIdx.x;
  const int bm = blockIdx.x * BM;
  const int bn = blockIdx.y * BN;
  const int tx = t & 15;   // 16 col-groups
  const int ty = t >> 4;   // 16 row-groups

  // loader indices
  const int arow = t >> 1;          // 0..127
  const int ak0 = (t & 1) * 8;      // 0 or 8
  const int bcol = t >> 2;          // 0..63
  const int bk0 = (t & 3) * 4;      // 0,4,8,12

  float acc[8][4] = {};

  for (int kt = 0; kt < K; kt += BK) {
    float4 av0 = *(const float4*)&A[(size_t)(bm + arow) * K + kt + ak0];
    float4 av1 = *(const float4*)&A[(size_t)(bm + arow) * K + kt + ak0 + 4];
    if (TRANSFORM) {
      const float* tA = ta + kt + ak0;
      const float* tC = tc + kt + ak0;
      av0.x = fmaf(av0.x, tA[0], tC[0]);
      av0.y = fmaf(av0.y, tA[1], tC[1]);
      av0.z = fmaf(av0.z, tA[2], tC[2]);
      av0.w = fmaf(av0.w, tA[3], tC[3]);
      av1.x = fmaf(av1.x, tA[4], tC[4]);
      av1.y = fmaf(av1.y, tA[5], tC[5]);
      av1.z = fmaf(av1.z, tA[6], tC[6]);
      av1.w = fmaf(av1.w, tA[7], tC[7]);
    }
    As[ak0 + 0][arow] = av0.x;
    As[ak0 + 1][arow] = av0.y;
    As[ak0 + 2][arow] = av0.z;
    As[ak0 + 3][arow] = av0.w;
    As[ak0 + 4][arow] = av1.x;
    As[ak0 + 5][arow] = av1.y;
    As[ak0 + 6][arow] = av1.z;
    As[ak0 + 7][arow] = av1.w;

    float4 bv = make_float4(0.f, 0.f, 0.f, 0.f);
    if (bn + bcol < Nn) {
      bv = *(const float4*)&W[(size_t)(bn + bcol) * K + kt + bk0];
    }
    Bs[bk0 + 0][bcol] = bv.x;
    Bs[bk0 + 1][bcol] = bv.y;
    Bs[bk0 + 2][bcol] = bv.z;
    Bs[bk0 + 3][bcol] = bv.w;

    __syncthreads();

#pragma unroll
    for (int kk = 0; kk < BK; ++kk) {
      const float4 a0 = *(const float4*)&As[kk][ty * 8];
      const float4 a1 = *(const float4*)&As[kk][ty * 8 + 4];
      const float4 b = *(const float4*)&Bs[kk][tx * 4];
      const float ar[8] = {a0.x, a0.y, a0.z, a0.w, a1.x, a1.y, a1.z, a1.w};
      const float br[4] = {b.x, b.y, b.z, b.w};
#pragma unroll
      for (int i = 0; i < 8; ++i)
#pragma unroll
        for (int j = 0; j < 4; ++j) acc[i][j] = fmaf(ar[i], br[j], acc[i][j]);
    }
    __syncthreads();
  }

  const int col = bn + tx * 4;
  if (col < Nn) {
    const float4 bb = *(const float4*)&bias[col];
#pragma unroll
    for (int i = 0; i < 8; ++i) {
      const int row = bm + ty * 8 + i;
      float4 o;
      o.x = acc[i][0] + bb.x;
      o.y = acc[i][1] + bb.y;
      o.z = acc[i][2] + bb.z;
      o.w = acc[i][3] + bb.w;
      *(float4*)&C[(size_t)row * Nn + col] = o;
    }
  }
}

// ---------------------------------------------------------------------------
// Column stats partials: per (column, row-block) sums of x and x^2.
// grid (C/16, NBLK), block 256 = 16 row-threads x 16 cols.
// ---------------------------------------------------------------------------
__global__ __launch_bounds__(256) void colstats_partial(
    const float* __restrict__ Y, float* __restrict__ pS,
    float* __restrict__ pQ, int rowsPer, int C) {
  const int t = threadIdx.x;
  const int colLocal = t & 15;
  const int col = blockIdx.x * 16 + colLocal;
  const int rl = t >> 4;  // 0..15
  const int r0 = blockIdx.y * rowsPer;
  float s = 0.f, q = 0.f;
  for (int k = 0; k < rowsPer / 16; ++k) {
    const float x = Y[(size_t)(r0 + rl + 16 * k) * C + col];
    s += x;
    q += x * x;
  }
  __shared__ float rs[16][16];
  __shared__ float rq[16][16];
  rs[rl][colLocal] = s;
  rq[rl][colLocal] = q;
  __syncthreads();
  if (t < 16) {
    float S = 0.f, Q = 0.f;
#pragma unroll
    for (int i = 0; i < 16; ++i) {
      S += rs[i][t];
      Q += rq[i][t];
    }
    pS[blockIdx.y * C + blockIdx.x * 16 + t] = S;
    pQ[blockIdx.y * C + blockIdx.x * 16 + t] = Q;
  }
}

// ---------------------------------------------------------------------------
// BN finalize: a[j] = g[j]*rsqrt(var+eps), c[j] = be[j] - mu*a[j]
// ---------------------------------------------------------------------------
__global__ void bn_finalize(const float* __restrict__ pS,
                            const float* __restrict__ pQ,
                            const float* __restrict__ g,
                            const float* __restrict__ be,
                            float* __restrict__ a, float* __restrict__ c,
                            int nb, int C, float invN) {
  const int col = blockIdx.x * blockDim.x + threadIdx.x;
  if (col >= C) return;
  float S = 0.f, Q = 0.f;
  for (int b = 0; b < nb; ++b) {
    S += pS[b * C + col];
    Q += pQ[b * C + col];
  }
  const float mu = S * invN;
  const float var = Q * invN - mu * mu;
  const float inv = rsqrtf(var + BN_EPS);
  const float aa = g[col] * inv;
  a[col] = aa;
  c[col] = be[col] - mu * aa;
}

// ---------------------------------------------------------------------------
// Final: out[n] = partial[n] + sum_j (a2[j]*Y2[n,j] + c2[j])
// One wave per row, 4 rows per block.
// ---------------------------------------------------------------------------
__global__ __launch_bounds__(256) void final_kernel(
    const float* __restrict__ Y2, const float* __restrict__ a2,
    const float* __restrict__ c2, const float* __restrict__ partial,
    float* __restrict__ out, int C) {
  const int t = threadIdx.x;
  const int lane = t & 63;
  const int n = blockIdx.x * 4 + (t >> 6);
  const float* y = Y2 + (size_t)n * C;
  float acc = 0.f;
  for (int j = lane; j < C; j += 64) acc += fmaf(a2[j], y[j], c2[j]);
  acc = wave_reduce_sum(acc);
  if (lane == 0) out[n] = partial[n] + acc;
}

extern "C" void kernel_launch(void* const* d_in, const int* in_sizes, int n_in,
                              void* d_out, int out_size, void* d_ws,
                              size_t ws_size, hipStream_t stream) {
  const float* Xi_dense = (const float*)d_in[0];
  const float* Xv = (const float*)d_in[1];
  const float* Wd = (const float*)d_in[2];
  const float* bd = (const float*)d_in[3];
  const float* tables = (const float*)d_in[4];
  const float* W1 = (const float*)d_in[5];
  const float* b1 = (const float*)d_in[6];
  const float* g1 = (const float*)d_in[7];
  const float* be1 = (const float*)d_in[8];
  const float* W2 = (const float*)d_in[9];
  const float* b2 = (const float*)d_in[10];
  const float* g2 = (const float*)d_in[11];
  const float* be2 = (const float*)d_in[12];
  const float* bias_vec = (const float*)d_in[13];
  const int* Xi_cat = (const int*)d_in[14];

  constexpr int N = 16384;
  constexpr int DIN = 576;
  constexpr int H = 400;

  float* ws = (float*)d_ws;
  float* fm_first = ws;                     // N*576 = 9,437,184 floats
  float* Y1 = ws + (size_t)N * DIN;         // N*400 = 6,553,600 floats
  float* Y2 = fm_first;                     // alias: fm_first dead after GEMM1
  float* partial = Y1 + (size_t)N * H;      // N floats
  float* pS = partial + N;                  // 16*400
  float* pQ = pS + 16 * H;                  // 16*400
  float* a1 = pQ + 16 * H;
  float* c1 = a1 + H;
  float* a2 = c1 + H;
  float* c2 = a2 + H;

  embed_kernel<<<N / 4, 256, 0, stream>>>(Xi_dense, Xv, Wd, bd, tables,
                                          Xi_cat, bias_vec, fm_first, partial);

  dim3 gg(N / 128, (H + 63) / 64);
  gemm_tn<false><<<gg, 256, 0, stream>>>(fm_first, W1, b1, nullptr, nullptr,
                                         Y1, N, H, DIN);

  colstats_partial<<<dim3(H / 16, 16), 256, 0, stream>>>(Y1, pS, pQ, N / 16,
                                                         H);
  bn_finalize<<<2, 256, 0, stream>>>(pS, pQ, g1, be1, a1, c1, 16, H,
                                     1.0f / N);

  gemm_tn<true><<<gg, 256, 0, stream>>>(Y1, W2, b2, a1, c1, Y2, N, H, H);

  colstats_partial<<<dim3(H / 16, 16), 256, 0, stream>>>(Y2, pS, pQ, N / 16,
                                                         H);
  bn_finalize<<<2, 256, 0, stream>>>(pS, pQ, g2, be2, a2, c2, 16, H,
                                     1.0f / N);

  final_kernel<<<N / 4, 256, 0, stream>>>(Y2, a2, c2, partial, (float*)d_out,
                                          H);
}

// Round 2
// 133.306 us; speedup vs baseline: 2.1883x; 2.1883x over previous
//
#include <hip/hip_runtime.h>

#define BN_EPS 1e-5f

typedef unsigned short u16;
typedef __attribute__((ext_vector_type(8))) short bf16x8;
typedef __attribute__((ext_vector_type(4))) float f32x4;

__device__ __forceinline__ u16 f2bf(float x) {
  union { float f; unsigned int u; } v; v.f = x;
  unsigned int r = v.u + 0x7fffu + ((v.u >> 16) & 1u);
  return (u16)(r >> 16);
}
__device__ __forceinline__ float bf2f(u16 h) {
  union { unsigned int u; float f; } v; v.u = ((unsigned int)h) << 16;
  return v.f;
}

__device__ __forceinline__ float wave_reduce_sum(float v) {
#pragma unroll
  for (int off = 1; off < 64; off <<= 1) v += __shfl_xor(v, off, 64);
  return v;
}

// ---------------------------------------------------------------------------
// Kernel 1: embeddings -> fm_first (N x 576, bf16), plus
// partial[n] = sum(fm_first) + fm_second row-sum + bias_vec  (fp32)
// One wave per row; element idx = f*16+e; lane owns idx = lane + 64k.
// ---------------------------------------------------------------------------
__global__ __launch_bounds__(256) void embed_kernel(
    const float* __restrict__ Xi_dense, const float* __restrict__ Xv,
    const float* __restrict__ Wd, const float* __restrict__ bd,
    const float* __restrict__ tables, const int* __restrict__ Xi_cat,
    const float* __restrict__ bias_vec,
    u16* __restrict__ fm_first, float* __restrict__ partial) {
  const int t = threadIdx.x;
  const int lane = t & 63;
  const int n = blockIdx.x * 4 + (t >> 6);

  const float* xv = Xv + n * 36;
  float sum_all = 0.f, s_e = 0.f, q_e = 0.f;

#pragma unroll
  for (int k = 0; k < 9; ++k) {
    const int idx = lane + 64 * k;
    const int f = idx >> 4;
    const int e = idx & 15;
    float val;
    if (f < 26) {
      val = Xi_dense[n * 26 + f] * Wd[f * 16 + e] + bd[f * 16 + e];
    } else {
      const int fc = f - 26;
      const int row = Xi_cat[n * 10 + fc];
      val = tables[(size_t)fc * 200000 * 16 + (size_t)row * 16 + e];
    }
    val *= xv[f];
    fm_first[(size_t)n * 576 + idx] = f2bf(val);
    sum_all += val;
    s_e += val;
    q_e += val * val;
  }

  float s_tot = s_e;
  s_tot += __shfl_xor(s_tot, 16, 64);
  s_tot += __shfl_xor(s_tot, 32, 64);
  float q_tot = q_e;
  q_tot += __shfl_xor(q_tot, 16, 64);
  q_tot += __shfl_xor(q_tot, 32, 64);

  const float fm2 = 0.5f * (s_tot * s_tot - q_tot);  // replicated 4x per e
  const float red1 = wave_reduce_sum(sum_all);
  const float red2 = wave_reduce_sum(fm2) * 0.25f;
  if (lane == 0) partial[n] = red1 + red2 + bias_vec[n];
}

// ---------------------------------------------------------------------------
// bf16 MFMA GEMM: Y(M x Nn) = A(M x K) @ W^T + bias, all operands bf16,
// fp32 accumulate. W is (Nn x ldw) row-major bf16 (rows >= Nn read as 0).
// Epilogue: bf16 store (cols [Nn,Ncap) zero-filled) + per-block column
// sum/sumsq partials -> pS/pQ[col * gridDim.x + blockIdx.x].
// BM=128 BN=64 BK=32, 256 threads = 4 waves (2x2), 4x2 16x16 frags/wave.
// ---------------------------------------------------------------------------
__global__ __launch_bounds__(256) void gemm_bf16(
    const u16* __restrict__ A, int lda,
    const u16* __restrict__ W, int ldw, int Nn,
    const float* __restrict__ bias,
    u16* __restrict__ Y, int ldc, int Ncap,
    float* __restrict__ pS, float* __restrict__ pQ, int K) {
  constexpr int PK = 40;  // 32 + 8 pad (80B stride -> 2-way bank alias, free)
  __shared__ u16 As[128][PK];
  __shared__ u16 Bs[64][PK];
  __shared__ float rS[2][2][2][16];
  __shared__ float rQ[2][2][2][16];

  const int t = threadIdx.x;
  const int bm = blockIdx.x * 128;
  const int bn = blockIdx.y * 64;
  const int wid = t >> 6, lane = t & 63;
  const int wr = wid >> 1, wc = wid & 1;
  const int lr = lane & 15, lk = (lane >> 4) * 8;

  const int ar0 = t >> 2;             // 0..63
  const int akp = (t & 3) * 8;        // 0,8,16,24

  f32x4 acc[4][2] = {};

  for (int kt = 0; kt < K; kt += 32) {
    bf16x8 a0 = *(const bf16x8*)&A[(size_t)(bm + ar0) * lda + kt + akp];
    bf16x8 a1 = *(const bf16x8*)&A[(size_t)(bm + 64 + ar0) * lda + kt + akp];
    bf16x8 bv = {};
    if (bn + ar0 < Nn)
      bv = *(const bf16x8*)&W[(size_t)(bn + ar0) * ldw + kt + akp];
    *(bf16x8*)&As[ar0][akp] = a0;
    *(bf16x8*)&As[64 + ar0][akp] = a1;
    *(bf16x8*)&Bs[ar0][akp] = bv;
    __syncthreads();

    bf16x8 af[4], bfv[2];
#pragma unroll
    for (int mf = 0; mf < 4; ++mf)
      af[mf] = *(const bf16x8*)&As[wr * 64 + mf * 16 + lr][lk];
#pragma unroll
    for (int nf = 0; nf < 2; ++nf)
      bfv[nf] = *(const bf16x8*)&Bs[wc * 32 + nf * 16 + lr][lk];
#pragma unroll
    for (int mf = 0; mf < 4; ++mf)
#pragma unroll
      for (int nf = 0; nf < 2; ++nf)
        acc[mf][nf] = __builtin_amdgcn_mfma_f32_16x16x32_bf16(
            af[mf], bfv[nf], acc[mf][nf], 0, 0, 0);
    __syncthreads();
  }

  // epilogue: bias add, bf16 store, column partial stats
  const int l4 = (lane >> 4) * 4;
#pragma unroll
  for (int nf = 0; nf < 2; ++nf) {
    const int col = bn + wc * 32 + nf * 16 + lr;
    const float bb = (col < Nn) ? bias[col] : 0.f;
    float s = 0.f, q = 0.f;
#pragma unroll
    for (int mf = 0; mf < 4; ++mf) {
#pragma unroll
      for (int r = 0; r < 4; ++r) {
        const int row = bm + wr * 64 + mf * 16 + l4 + r;
        const float v = acc[mf][nf][r] + bb;
        s += v;
        q += v * v;
        if (col < Nn)
          Y[(size_t)row * ldc + col] = f2bf(v);
        else if (col < Ncap)
          Y[(size_t)row * ldc + col] = 0;
      }
    }
    s += __shfl_xor(s, 16, 64);
    s += __shfl_xor(s, 32, 64);
    q += __shfl_xor(q, 16, 64);
    q += __shfl_xor(q, 32, 64);
    if (lane < 16) {
      rS[wc][nf][wr][lr] = s;
      rQ[wc][nf][wr][lr] = q;
    }
  }
  __syncthreads();
  if (t < 64) {
    const int wcc = t >> 5, nff = (t >> 4) & 1, c = t & 15;
    const float S = rS[wcc][nff][0][c] + rS[wcc][nff][1][c];
    const float Q = rQ[wcc][nff][0][c] + rQ[wcc][nff][1][c];
    pS[(size_t)(bn + t) * gridDim.x + blockIdx.x] = S;
    pQ[(size_t)(bn + t) * gridDim.x + blockIdx.x] = Q;
  }
}

// ---------------------------------------------------------------------------
// BN finalize: a[j]=g[j]*rsqrt(var+eps), c[j]=be[j]-mu*a[j]
// ---------------------------------------------------------------------------
__global__ void bn_finalize(const float* __restrict__ pS,
                            const float* __restrict__ pQ,
                            const float* __restrict__ g,
                            const float* __restrict__ be,
                            float* __restrict__ a, float* __restrict__ c,
                            int nb, int C, float invN) {
  const int col = blockIdx.x * blockDim.x + threadIdx.x;
  if (col >= C) return;
  float S = 0.f, Q = 0.f;
  for (int b = 0; b < nb; ++b) {
    S += pS[(size_t)col * nb + b];
    Q += pQ[(size_t)col * nb + b];
  }
  const float mu = S * invN;
  const float var = Q * invN - mu * mu;
  const float aa = g[col] * rsqrtf(var + BN_EPS);
  a[col] = aa;
  c[col] = be[col] - mu * aa;
}

// ---------------------------------------------------------------------------
// cvt fp32 -> bf16 elementwise
// ---------------------------------------------------------------------------
__global__ void cvt_bf16(const float* __restrict__ X, u16* __restrict__ Yh,
                         int n) {
  const int i = blockIdx.x * 256 + threadIdx.x;
  if (i < n) Yh[i] = f2bf(X[i]);
}

// ---------------------------------------------------------------------------
// Fold BN1 affine into W2:  W2p[i][j] = bf16(W2[i][j]*a1[j]), K-pad to 416
// ---------------------------------------------------------------------------
__global__ void fold_W2(const float* __restrict__ W2,
                        const float* __restrict__ a1, u16* __restrict__ W2p) {
  const int i = blockIdx.x * 256 + threadIdx.x;
  if (i >= 400 * 416) return;
  const int r = i / 416;
  const int j = i - r * 416;
  W2p[i] = (j < 400) ? f2bf(W2[r * 400 + j] * a1[j]) : (u16)0;
}

// ---------------------------------------------------------------------------
// b2p[i] = b2[i] + sum_j W2[i][j]*c1[j]   (one wave per row)
// ---------------------------------------------------------------------------
__global__ __launch_bounds__(256) void fold_b2(const float* __restrict__ W2,
                                               const float* __restrict__ c1,
                                               const float* __restrict__ b2,
                                               float* __restrict__ b2p) {
  const int wid = (blockIdx.x * 256 + threadIdx.x) >> 6;
  const int lane = threadIdx.x & 63;
  if (wid >= 400) return;
  float s = 0.f;
  for (int j = lane; j < 400; j += 64) s += W2[wid * 400 + j] * c1[j];
  s = wave_reduce_sum(s);
  if (lane == 0) b2p[wid] = b2[wid] + s;
}

// ---------------------------------------------------------------------------
// Final: out[n] = partial[n] + sum_j (a2[j]*Y2h[n,j] + c2[j])
// ---------------------------------------------------------------------------
__global__ __launch_bounds__(256) void final_kernel(
    const u16* __restrict__ Y2, const float* __restrict__ a2,
    const float* __restrict__ c2, const float* __restrict__ partial,
    float* __restrict__ out, int C) {
  const int t = threadIdx.x;
  const int lane = t & 63;
  const int n = blockIdx.x * 4 + (t >> 6);
  const u16* y = Y2 + (size_t)n * C;
  float acc = 0.f;
  for (int j = lane; j < C; j += 64) acc += fmaf(a2[j], bf2f(y[j]), c2[j]);
  acc = wave_reduce_sum(acc);
  if (lane == 0) out[n] = partial[n] + acc;
}

extern "C" void kernel_launch(void* const* d_in, const int* in_sizes, int n_in,
                              void* d_out, int out_size, void* d_ws,
                              size_t ws_size, hipStream_t stream) {
  const float* Xi_dense = (const float*)d_in[0];
  const float* Xv = (const float*)d_in[1];
  const float* Wd = (const float*)d_in[2];
  const float* bd = (const float*)d_in[3];
  const float* tables = (const float*)d_in[4];
  const float* W1 = (const float*)d_in[5];
  const float* b1 = (const float*)d_in[6];
  const float* g1 = (const float*)d_in[7];
  const float* be1 = (const float*)d_in[8];
  const float* W2 = (const float*)d_in[9];
  const float* b2 = (const float*)d_in[10];
  const float* g2 = (const float*)d_in[11];
  const float* be2 = (const float*)d_in[12];
  const float* bias_vec = (const float*)d_in[13];
  const int* Xi_cat = (const int*)d_in[14];

  constexpr int N = 16384;
  constexpr int DIN = 576;
  constexpr int H = 400;
  constexpr int KP = 416;   // H padded to multiple of 32
  constexpr int MB = 128;   // M blocks (N/128)

  // workspace layout (u16 regions first, then fp32; all even counts)
  u16* fm_first = (u16*)d_ws;                        // N*576
  u16* Y1h = fm_first + (size_t)N * DIN;             // N*416
  u16* Y2h = Y1h + (size_t)N * KP;                   // N*400
  u16* W1h = Y2h + (size_t)N * H;                    // 400*576
  u16* W2p = W1h + (size_t)H * DIN;                  // 400*416
  float* fptr = (float*)(W2p + (size_t)H * KP);
  float* partial = fptr;                             // N
  float* pS = partial + N;                           // 448*128
  float* pQ = pS + 448 * MB;                         // 448*128
  float* a1 = pQ + 448 * MB;
  float* c1 = a1 + H;
  float* a2 = c1 + H;
  float* c2 = a2 + H;
  float* b2p = c2 + H;                               // 400

  embed_kernel<<<N / 4, 256, 0, stream>>>(Xi_dense, Xv, Wd, bd, tables,
                                          Xi_cat, bias_vec, fm_first, partial);

  cvt_bf16<<<(H * DIN + 255) / 256, 256, 0, stream>>>(W1, W1h, H * DIN);

  dim3 gg(MB, 7);  // 7*64 = 448 >= 400
  gemm_bf16<<<gg, 256, 0, stream>>>(fm_first, DIN, W1h, DIN, H, b1,
                                    Y1h, KP, KP, pS, pQ, DIN);
  bn_finalize<<<2, 256, 0, stream>>>(pS, pQ, g1, be1, a1, c1, MB, H,
                                     1.0f / N);

  fold_W2<<<(H * KP + 255) / 256, 256, 0, stream>>>(W2, a1, W2p);
  fold_b2<<<100, 256, 0, stream>>>(W2, c1, b2, b2p);

  gemm_bf16<<<gg, 256, 0, stream>>>(Y1h, KP, W2p, KP, H, b2p,
                                    Y2h, H, H, pS, pQ, KP);
  bn_finalize<<<2, 256, 0, stream>>>(pS, pQ, g2, be2, a2, c2, MB, H,
                                     1.0f / N);

  final_kernel<<<N / 4, 256, 0, stream>>>(Y2h, a2, c2, partial,
                                          (float*)d_out, H);
}